// Round 2
// baseline (245.516 us; speedup 1.0000x reference)
//
#include <hip/hip_runtime.h>

#define CHANNELS 3
#define HW 512
#define KS 15
#define GPAD 7
#define TILE 64
#define HT (TILE + 2 * GPAD)   // 78 mid rows (output tile + vertical halo)
#define MSTR 65                // mid LDS stride: odd -> all LDS phases <=2-way bank aliasing (free)
#define WIN (16 + KS - 1)      // 30-tap window per 16-output chunk

// LDS = 78*65*4 = 20280 B -> 8 blocks/CU; 8 blocks x 4 waves = 32 waves/CU.
// launch_bounds(256,8): 8 waves/EU -> VGPR capped at 64.
__global__ __launch_bounds__(256, 8)
void gauss_blur_kernel(const float* __restrict__ x,
                       const float* __restrict__ sigma,
                       float* __restrict__ out) {
    // Single LDS buffer: horizontally-filtered "mid" tile, 78 rows x 64 cols.
    __shared__ float mid_s[HT * MSTR];

    const int tid   = threadIdx.x;   // 0..255
    const int tileX = blockIdx.x;    // 0..7
    const int tileY = blockIdx.y;    // 0..7
    const int bc    = blockIdx.z;    // 0..B*C-1
    const int b     = bc / CHANNELS;

    // per-batch 1D Gaussian weights; wave-uniform -> pin to SGPRs (frees 15 VGPRs;
    // v_fma_f32 can source one SGPR operand directly).
    float w[KS];
    {
        const float s = sigma[b];
        const float inv_denom = 1.0f / (2.0f * s * s + 1e-8f);
        float g[KS];
        float sum = 0.0f;
        #pragma unroll
        for (int i = 0; i < KS; ++i) {
            const float d = (float)(i - GPAD);
            g[i] = __expf(-d * d * inv_denom);
            sum += g[i];
        }
        const float inv = 1.0f / sum;
        #pragma unroll
        for (int i = 0; i < KS; ++i)
            w[i] = __int_as_float(__builtin_amdgcn_readfirstlane(__float_as_int(g[i] * inv)));
    }

    const size_t plane = (size_t)HW * HW;
    const float* xp = x + (size_t)bc * plane;
    float* op       = out + (size_t)bc * plane;
    const int gx0 = tileX * TILE;          // first output col of tile
    const int gy0 = tileY * TILE - GPAD;   // first mid row (global)
    // interior tiles: every 32-float window [gx0+16ch-8, +32) is fully in-image
    const bool xin = (tileX > 0) && (tileX < (HW / TILE) - 1);

    // ---- phase H: horizontal pass, global -> registers -> mid in LDS.
    // Item i -> (row r = i>>2, 16-col chunk ch = i&3). 312 items over 256 threads.
    // Window: 32 floats at global col c0 = gx0+16ch-8 (32B-aligned in interior);
    // taps for output o use win[o+1 .. o+15]. One barrier total per block. ----
    for (int i = tid; i < HT * 4; i += 256) {
        const int r  = i >> 2;
        const int ch = i & 3;
        const int gy = gy0 + r;
        float* dst = &mid_s[r * MSTR + 16 * ch];
        if ((unsigned)gy >= (unsigned)HW) {
            // out-of-image row: zero-padded conv -> mid row is zero
            #pragma unroll
            for (int o = 0; o < 16; ++o) dst[o] = 0.0f;
            continue;
        }
        const int c0 = gx0 + 16 * ch - 8;
        const float* rowp = xp + (size_t)gy * HW + c0;
        float win[32];
        if (xin) {
            #pragma unroll
            for (int k = 0; k < 8; ++k) {
                const float4 v = *(const float4*)(rowp + 4 * k);
                win[4 * k + 0] = v.x; win[4 * k + 1] = v.y;
                win[4 * k + 2] = v.z; win[4 * k + 3] = v.w;
            }
        } else {
            #pragma unroll
            for (int k = 0; k < 32; ++k) {
                const int gc = c0 + k;
                win[k] = ((unsigned)gc < (unsigned)HW) ? rowp[k] : 0.0f;
            }
        }
        float acc[16];
        #pragma unroll
        for (int o = 0; o < 16; ++o) acc[o] = 0.0f;
        #pragma unroll
        for (int j = 0; j < WIN; ++j) {
            const float v = win[j + 1];
            const int lo = (j - (KS - 1)) > 0 ? (j - (KS - 1)) : 0;
            const int hi = (j < 15) ? j : 15;
            #pragma unroll
            for (int o = lo; o <= hi; ++o)
                acc[o] = fmaf(w[j - o], v, acc[o]);
            // acc[j-14] is complete once tap j applied -> store early: caps live
            // registers (win[k<=j] also dead) and overlaps ds_write with FMA.
            if (j >= KS - 1) dst[j - (KS - 1)] = acc[j - (KS - 1)];
        }
    }
    __syncthreads();

    // ---- phase V: vertical pass from mid, accumulate on load; coalesced
    // 256B/wave stores. Lane layout: c = tid&63 (row-contig ds_read, 2-way free),
    // r0 = (tid>>6)*16. ----
    {
        const int c  = tid & (TILE - 1);
        const int r0 = (tid >> 6) * 16;
        float vacc[16];
        #pragma unroll
        for (int o = 0; o < 16; ++o) vacc[o] = 0.0f;
        #pragma unroll
        for (int j = 0; j < WIN; ++j) {
            const float v = mid_s[(r0 + j) * MSTR + c];
            const int lo = (j - (KS - 1)) > 0 ? (j - (KS - 1)) : 0;
            const int hi = (j < 15) ? j : 15;
            #pragma unroll
            for (int o = lo; o <= hi; ++o) vacc[o] = fmaf(w[j - o], v, vacc[o]);
        }
        const int gx = gx0 + c;
        float* colp = op + (size_t)(tileY * TILE + r0) * HW + gx;
        #pragma unroll
        for (int o = 0; o < 16; ++o)
            colp[(size_t)o * HW] = vacc[o];
    }
}

extern "C" void kernel_launch(void* const* d_in, const int* in_sizes, int n_in,
                              void* d_out, int out_size, void* d_ws, size_t ws_size,
                              hipStream_t stream) {
    const float* x     = (const float*)d_in[0];
    const float* sigma = (const float*)d_in[1];
    float* out         = (float*)d_out;
    const int B = in_sizes[1];  // 32
    dim3 grid(HW / TILE, HW / TILE, B * CHANNELS);
    gauss_blur_kernel<<<grid, dim3(256, 1, 1), 0, stream>>>(x, sigma, out);
}